// Round 1
// baseline (1035.613 us; speedup 1.0000x reference)
//
#include <hip/hip_runtime.h>
#include <stdint.h>

// ---------------- types ----------------
typedef __attribute__((ext_vector_type(8))) short short8;   // 8 x bf16 (4 VGPR) MFMA A/B frag
typedef __attribute__((ext_vector_type(4))) short short4v;  // 8B packed LDS write
typedef __attribute__((ext_vector_type(4))) float float4v;  // MFMA C/D frag

__device__ __forceinline__ short f2bf(float f) {
  uint32_t u = __builtin_bit_cast(uint32_t, f);
  u += 0x7FFFu + ((u >> 16) & 1u);   // round-to-nearest-even
  return (short)(u >> 16);
}

// ---------------- constants ----------------
// DIM=512, HEADS=8, D=64, N=64, B=2048 windows, MLON=64, PER_LAT=225
#define XPITCH 520   // 512 + 8: row stride 1040B = 260 dw == 4 mod 32 -> conflict-light b128
#define QPITCH 72    // 64 + 8:  row stride 144B = 36 dw == 4 mod 32

// =====================================================================
// Kernel 1: convert weights to bf16 in workspace
// =====================================================================
__global__ void prep_weights(const float* __restrict__ wq, const float* __restrict__ wp,
                             short* __restrict__ wq_b, short* __restrict__ wp_b) {
  int i = blockIdx.x * blockDim.x + threadIdx.x;
  int stride = gridDim.x * blockDim.x;
  for (int j = i; j < 786432 / 4; j += stride) {
    float4 v = ((const float4*)wq)[j];
    short4v t = {f2bf(v.x), f2bf(v.y), f2bf(v.z), f2bf(v.w)};
    ((short4v*)wq_b)[j] = t;
  }
  for (int j = i; j < 262144 / 4; j += stride) {
    float4 v = ((const float4*)wp)[j];
    short4v t = {f2bf(v.x), f2bf(v.y), f2bf(v.z), f2bf(v.w)};
    ((short4v*)wp_b)[j] = t;
  }
}

// =====================================================================
// Kernel 2: fused QKV-GEMM + window attention.  1 block = 1 window (64 tokens).
// 512 threads = 8 waves. Per round of 2 heads:
//   phase1: 24 strips (2 heads x {Qt,Kt,V} x 4 strips), 3 per wave.
//     Qt/Kt computed as W*X^T (A=W rows from global bf16, B=X^T from LDS);
//     V computed as X*W^T column-strips (A=X from LDS, B=W rows from global).
//     C-layout epilogues produce packed 4xbf16 (b64) writes into
//     Qs[n][d] (scaled by 1/8), Ks[m][d], Vt[d][m].
//   phase2: wave -> (head, 16-row strip): S=Qs*Ks^T + analytic earth bias,
//     row softmax via shfl_xor(1,2,4,8) within 16-lane groups, P->Qs rows
//     (wave-local overwrite), O=P*Vt, bf16 store to attn workspace.
// =====================================================================
__global__ __launch_bounds__(512, 2)
void qkv_attn(const float* __restrict__ x, const short* __restrict__ wq,
              const float* __restrict__ bqkv, const float* __restrict__ btab,
              short* __restrict__ attn) {
  __shared__ short Xs[64 * XPITCH];        // 66,560 B
  __shared__ short Qs[2][64 * QPITCH];     // 18,432 B
  __shared__ short Ks[2][64 * QPITCH];     // 18,432 B
  __shared__ short Vt[2][64 * QPITCH];     // 18,432 B   total 121,856 B

  const int b    = blockIdx.x;
  const int tid  = threadIdx.x;
  const int lane = tid & 63;
  const int w    = tid >> 6;       // wave 0..7
  const int l16  = lane & 15;
  const int quad = lane >> 4;      // 0..3
  const int lat  = b >> 6;         // MLON = 64

  // ---- stage X window into LDS as bf16 ----
  const float* xw = x + (size_t)b * (64 * 512);
  for (int c = tid; c < 64 * 128; c += 512) {   // float4 chunks
    int n = c >> 7, kc = c & 127;
    float4 v = *(const float4*)(xw + n * 512 + kc * 4);
    short4v t = {f2bf(v.x), f2bf(v.y), f2bf(v.z), f2bf(v.w)};
    *(short4v*)&Xs[n * XPITCH + kc * 4] = t;
  }
  __syncthreads();

  for (int h0 = 0; h0 < 8; h0 += 2) {
    // ---------------- phase 1: QKV GEMMs ----------------
    for (int s = w; s < 24; s += 8) {
      const int hsel  = s / 12;        // 0/1
      const int rem   = s % 12;
      const int mat   = rem >> 2;      // 0=Qt, 1=Kt, 2=V
      const int strip = rem & 3;
      const int h     = h0 + hsel;
      const short* Wbase = wq + (mat * 512 + h * 64 + strip * 16) * 512;

      float4v acc[4] = {};
      if (mat < 2) {
        // Qt/Kt: out rows d in [strip*16,+16), cols n in [0,64)
        const short* Arow = Wbase + l16 * 512 + quad * 8;
        for (int kk = 0; kk < 512; kk += 32) {
          short8 a = *(const short8*)(Arow + kk);
#pragma unroll
          for (int t = 0; t < 4; ++t) {
            short8 bf = *(const short8*)&Xs[(t * 16 + l16) * XPITCH + kk + quad * 8];
            acc[t] = __builtin_amdgcn_mfma_f32_16x16x32_bf16(a, bf, acc[t], 0, 0, 0);
          }
        }
        float bias[4];
#pragma unroll
        for (int i = 0; i < 4; ++i)
          bias[i] = bqkv[mat * 512 + h * 64 + strip * 16 + quad * 4 + i];
        short* dst = (mat == 0) ? &Qs[hsel][0] : &Ks[hsel][0];
        const float scale = (mat == 0) ? 0.125f : 1.0f;   // fold q-scale (exact pow2)
#pragma unroll
        for (int t = 0; t < 4; ++t) {
          int n = t * 16 + l16;
          short4v pk;
#pragma unroll
          for (int i = 0; i < 4; ++i) pk[i] = f2bf((acc[t][i] + bias[i]) * scale);
          *(short4v*)&dst[n * QPITCH + strip * 16 + quad * 4] = pk;  // [n][d] packed
        }
      } else {
        // V: out rows m in [0,64), col-strip d in [strip*16,+16)
        const short* Brow = Wbase + l16 * 512 + quad * 8;
        for (int kk = 0; kk < 512; kk += 32) {
          short8 bf = *(const short8*)(Brow + kk);
#pragma unroll
          for (int t = 0; t < 4; ++t) {
            short8 a = *(const short8*)&Xs[(t * 16 + l16) * XPITCH + kk + quad * 8];
            acc[t] = __builtin_amdgcn_mfma_f32_16x16x32_bf16(a, bf, acc[t], 0, 0, 0);
          }
        }
        float bias = bqkv[1024 + h * 64 + strip * 16 + l16];
#pragma unroll
        for (int t = 0; t < 4; ++t) {
          // lane holds V[m = t*16 + quad*4 + i][d = strip*16 + l16]
          short4v pk;
#pragma unroll
          for (int i = 0; i < 4; ++i) pk[i] = f2bf(acc[t][i] + bias);
          *(short4v*)&Vt[hsel][(strip * 16 + l16) * QPITCH + t * 16 + quad * 4] = pk; // [d][m]
        }
      }
    }
    __syncthreads();

    // ---------------- phase 2: attention ----------------
    {
      const int hsel = w >> 2;
      const int h    = h0 + hsel;
      const int n0   = (w & 3) * 16;

      // S = Q * K^T  (K-dim = d = 64)
      float4v s4[4] = {};
#pragma unroll
      for (int kd = 0; kd < 64; kd += 32) {
        short8 a = *(const short8*)&Qs[hsel][(n0 + l16) * QPITCH + kd + quad * 8];
#pragma unroll
        for (int t = 0; t < 4; ++t) {
          short8 bf = *(const short8*)&Ks[hsel][(t * 16 + l16) * QPITCH + kd + quad * 8];
          s4[t] = __builtin_amdgcn_mfma_f32_16x16x32_bf16(a, bf, s4[t], 0, 0, 0);
        }
      }
      // analytic earth bias (skips rel_idx input entirely)
#pragma unroll
      for (int t = 0; t < 4; ++t) {
        int m = t * 16 + l16;
#pragma unroll
        for (int i = 0; i < 4; ++i) {
          int n = n0 + quad * 4 + i;
          int idx = ((n >> 3) - (m >> 3) + 7) * 15 + ((n & 7) - (m & 7) + 7) + lat * 225;
          s4[t][i] += btab[idx * 8 + h];
        }
      }
      // row softmax: row n held at fixed reg i across 16 lanes of the quad
      float p[4][4];
#pragma unroll
      for (int i = 0; i < 4; ++i) {
        float mx = fmaxf(fmaxf(s4[0][i], s4[1][i]), fmaxf(s4[2][i], s4[3][i]));
        mx = fmaxf(mx, __shfl_xor(mx, 1));
        mx = fmaxf(mx, __shfl_xor(mx, 2));
        mx = fmaxf(mx, __shfl_xor(mx, 4));
        mx = fmaxf(mx, __shfl_xor(mx, 8));
        float e0 = __expf(s4[0][i] - mx), e1 = __expf(s4[1][i] - mx);
        float e2 = __expf(s4[2][i] - mx), e3 = __expf(s4[3][i] - mx);
        float sm = e0 + e1 + e2 + e3;
        sm += __shfl_xor(sm, 1);
        sm += __shfl_xor(sm, 2);
        sm += __shfl_xor(sm, 4);
        sm += __shfl_xor(sm, 8);
        float inv = 1.0f / sm;
        p[0][i] = e0 * inv; p[1][i] = e1 * inv; p[2][i] = e2 * inv; p[3][i] = e3 * inv;
      }
      // P -> LDS (overwrite own Q rows; wave-local round trip)
#pragma unroll
      for (int t = 0; t < 4; ++t)
#pragma unroll
        for (int i = 0; i < 4; ++i)
          Qs[hsel][(n0 + quad * 4 + i) * QPITCH + t * 16 + l16] = f2bf(p[t][i]);
      __syncthreads();

      // O = P * V  (K-dim = m = 64)
      float4v o4[4] = {};
#pragma unroll
      for (int km = 0; km < 64; km += 32) {
        short8 a = *(const short8*)&Qs[hsel][(n0 + l16) * QPITCH + km + quad * 8];
#pragma unroll
        for (int t = 0; t < 4; ++t) {
          short8 bf = *(const short8*)&Vt[hsel][(t * 16 + l16) * QPITCH + km + quad * 8];
          o4[t] = __builtin_amdgcn_mfma_f32_16x16x32_bf16(a, bf, o4[t], 0, 0, 0);
        }
      }
      // store attn[b][n][h*64 + d] as bf16
      short* ob = attn + (size_t)b * (64 * 512);
#pragma unroll
      for (int t = 0; t < 4; ++t)
#pragma unroll
        for (int i = 0; i < 4; ++i)
          ob[(n0 + quad * 4 + i) * 512 + h * 64 + t * 16 + l16] = f2bf(o4[t][i]);
    }
    __syncthreads();   // protect Qs/Ks/Vt before next head round
  }
}

// =====================================================================
// Kernel 3: out = attn(131072x512 bf16) @ w_proj^T + b_proj   (fp32 out)
// 128x128x32 MFMA tiles, 4 waves each owning a 64x64 quadrant.
// =====================================================================
__global__ __launch_bounds__(256, 3)
void proj_gemm(const short* __restrict__ attn, const short* __restrict__ wp,
               const float* __restrict__ bproj, float* __restrict__ out) {
  __shared__ short As[128 * 32];
  __shared__ short Bs[128 * 32];
  const int n0   = blockIdx.x * 128;   // x fastest: 4 n-blocks share A rows in L2
  const int m0   = blockIdx.y * 128;
  const int tid  = threadIdx.x;
  const int lane = tid & 63;
  const int w    = tid >> 6;
  const int l16  = lane & 15;
  const int quad = lane >> 4;
  const int wm   = w >> 1, wn = w & 1;

  float4v acc[4][4] = {};

  for (int kk = 0; kk < 512; kk += 32) {
#pragma unroll
    for (int r = 0; r < 2; ++r) {
      int c = tid + r * 256;           // chunk: row = c>>2, kc = c&3 (8 elems each)
      int row = c >> 2, kc = c & 3;
      *(uint4*)&As[c * 8] = *(const uint4*)(attn + (size_t)(m0 + row) * 512 + kk + kc * 8);
      *(uint4*)&Bs[c * 8] = *(const uint4*)(wp + (size_t)(n0 + row) * 512 + kk + kc * 8);
    }
    __syncthreads();
    short8 a[4], bf[4];
#pragma unroll
    for (int ti = 0; ti < 4; ++ti)
      a[ti] = *(const short8*)&As[(wm * 64 + ti * 16 + l16) * 32 + quad * 8];
#pragma unroll
    for (int tj = 0; tj < 4; ++tj)
      bf[tj] = *(const short8*)&Bs[(wn * 64 + tj * 16 + l16) * 32 + quad * 8];
#pragma unroll
    for (int ti = 0; ti < 4; ++ti)
#pragma unroll
      for (int tj = 0; tj < 4; ++tj)
        acc[ti][tj] = __builtin_amdgcn_mfma_f32_16x16x32_bf16(a[ti], bf[tj], acc[ti][tj], 0, 0, 0);
    __syncthreads();
  }

  float bj[4];
#pragma unroll
  for (int tj = 0; tj < 4; ++tj) bj[tj] = bproj[n0 + wn * 64 + tj * 16 + l16];
#pragma unroll
  for (int ti = 0; ti < 4; ++ti)
#pragma unroll
    for (int i = 0; i < 4; ++i) {
      size_t rowoff = (size_t)(m0 + wm * 64 + ti * 16 + quad * 4 + i) * 512;
#pragma unroll
      for (int tj = 0; tj < 4; ++tj)
        out[rowoff + n0 + wn * 64 + tj * 16 + l16] = acc[ti][tj][i] + bj[tj];
    }
}

// =====================================================================
extern "C" void kernel_launch(void* const* d_in, const int* in_sizes, int n_in,
                              void* d_out, int out_size, void* d_ws, size_t ws_size,
                              hipStream_t stream) {
  const float* x     = (const float*)d_in[0];   // (2048, 64, 512)
  const float* wqkv  = (const float*)d_in[1];   // (1536, 512)
  const float* bqkv  = (const float*)d_in[2];   // (1536,)
  const float* wproj = (const float*)d_in[3];   // (512, 512)
  const float* bproj = (const float*)d_in[4];   // (512,)
  const float* btab  = (const float*)d_in[5];   // (7200, 8)
  // d_in[6] = rel_idx -- recomputed analytically in-kernel, not read.
  float* out = (float*)d_out;

  short* wq_b = (short*)d_ws;            // 786,432 bf16
  short* wp_b = wq_b + 786432;           // 262,144 bf16
  short* attn = wp_b + 262144;           // 67,108,864 bf16 (~128 MB); ws use ~130 MB

  prep_weights<<<256, 256, 0, stream>>>(wqkv, wproj, wq_b, wp_b);
  qkv_attn<<<2048, 512, 0, stream>>>(x, wq_b, bqkv, btab, attn);
  proj_gemm<<<dim3(4, 1024), 256, 0, stream>>>(attn, wp_b, bproj, out);
}